// Round 5
// baseline (763.400 us; speedup 1.0000x reference)
//
#include <hip/hip_runtime.h>

// Vector Quantizer (VQ-VAE) forward on MI355X.
// N=131072 rows, D=64, K=1024 codes, all fp32.
// Output (flat fp32): quantized[8388608] | loss[1] | perplexity[1] | indices[131072]
//
// Numerics (PROVEN round 3 — do not change): replicate np's fp32 distances
//   d_k = fp32( fp32(||x||^2 + ||e_k||^2) - fp32(2 * (x . e_k)) ), first-min argmin,
// dot = single sequential fmaf chain over d (BLAS microkernel order), all decisive
// ops via __f*_rn so -ffp-contract can't perturb rounding.
//
// R4 perf fix (resubmitted — R4 bench was a GPU-acquisition timeout, no data):
// round-3 ran at 441us with VGPR_Count=64 -> xv[64] spilled to scratch
// (WRITE_SIZE 89MB vs 34MB true output). Grid gives only 2 waves/SIMD
// (512 blocks), so the 64-VGPR cap bought nothing. __launch_bounds__(256,2)
// lifts the cap to ~256 VGPRs; k-loop unroll-by-2 gives two independent fma
// chains (ILP=2) to cover FMA latency at 2 waves/SIMD.

#define N_ROWS   131072
#define K_CODES  1024
#define DIM      64
#define OUT_LOSS 8388608
#define OUT_PERP 8388609
#define OUT_IDX  8388610

// ---------------- ws layout ----------------
// [0,8)        double sse
// [8,16)       pad
// [16,4112)    uint counts[1024]
// [4112,8208)  float embnorm[1024]

__global__ __launch_bounds__(256) void embnorm_kernel(const float* __restrict__ emb,
                                                      float* __restrict__ norms) {
    int k = blockIdx.x * blockDim.x + threadIdx.x;
    if (k < K_CODES) {
        const float* e = emb + (size_t)k * DIM;
        float r[8];
#pragma unroll
        for (int j = 0; j < 8; ++j) r[j] = __fmul_rn(e[j], e[j]);
#pragma unroll
        for (int i = 8; i < DIM; i += 8)
#pragma unroll
            for (int j = 0; j < 8; ++j) r[j] = __fadd_rn(r[j], __fmul_rn(e[i + j], e[i + j]));
        norms[k] = __fadd_rn(__fadd_rn(__fadd_rn(r[0], r[1]), __fadd_rn(r[2], r[3])),
                             __fadd_rn(__fadd_rn(r[4], r[5]), __fadd_rn(r[6], r[7])));
    }
}

__global__ __launch_bounds__(256, 2) void vq_kernel(const float* __restrict__ inp,
                                                    const float* __restrict__ emb,
                                                    const float* __restrict__ norms,
                                                    float* __restrict__ out,
                                                    unsigned int* __restrict__ counts,
                                                    double* __restrict__ sse) {
    const int row = blockIdx.x * 256 + threadIdx.x;

    // Row into registers (fully-unrolled constant indices -> SROA to VGPRs).
    float xv[DIM];
    const float4* xp = reinterpret_cast<const float4*>(inp + (size_t)row * DIM);
#pragma unroll
    for (int i = 0; i < DIM / 4; ++i) {
        float4 v = xp[i];
        xv[4 * i + 0] = v.x; xv[4 * i + 1] = v.y;
        xv[4 * i + 2] = v.z; xv[4 * i + 3] = v.w;
    }

    // s1 = ||x||^2 (numpy 8-acc pairwise; order argmin-invariant but kept exact).
    float r[8];
#pragma unroll
    for (int j = 0; j < 8; ++j) r[j] = __fmul_rn(xv[j], xv[j]);
#pragma unroll
    for (int i = 8; i < DIM; i += 8)
#pragma unroll
        for (int j = 0; j < 8; ++j) r[j] = __fadd_rn(r[j], __fmul_rn(xv[i + j], xv[i + j]));
    const float s1 = __fadd_rn(__fadd_rn(__fadd_rn(r[0], r[1]), __fadd_rn(r[2], r[3])),
                               __fadd_rn(__fadd_rn(r[4], r[5]), __fadd_rn(r[6], r[7])));

    // Argmin over codes — np fp32 rounding replicated exactly.
    // emb/norms addresses are wave-uniform -> scalar s_loads; FMA chain per k.
    // unroll 2: chains for k and k+1 are independent -> ILP=2, latency covered.
    float best = 3.402823466e38f;
    int   bidx = 0;
#pragma unroll 2
    for (int k = 0; k < K_CODES; ++k) {
        const float* e = emb + (size_t)k * DIM;
        float acc = 0.f;                       // sgemm: single sequential fma chain
#pragma unroll
        for (int d = 0; d < DIM; ++d) acc = __builtin_fmaf(xv[d], e[d], acc);
        float Dk = __fsub_rn(__fadd_rn(s1, norms[k]), __fmul_rn(2.0f, acc));
        if (Dk < best) { best = Dk; bidx = k; }   // strict <: first index wins ties
    }

    // Epilogue: gather winner, write quantized, accumulate SSE (loose thresholds).
    const float4* eb = reinterpret_cast<const float4*>(emb + (size_t)bidx * DIM);
    float4* qo = reinterpret_cast<float4*>(out + (size_t)row * DIM);
    float err = 0.f;
#pragma unroll
    for (int i = 0; i < DIM / 4; ++i) {
        float4 ev = eb[i];
        qo[i] = ev;
        float dx = ev.x - xv[4 * i + 0];
        float dy = ev.y - xv[4 * i + 1];
        float dz = ev.z - xv[4 * i + 2];
        float dw = ev.w - xv[4 * i + 3];
        err += dx * dx + dy * dy + dz * dz + dw * dw;
    }
    out[OUT_IDX + row] = (float)bidx;
    atomicAdd(&counts[bidx], 1u);

    __shared__ float red[256];
    red[threadIdx.x] = err;
    __syncthreads();
#pragma unroll
    for (int s = 128; s > 0; s >>= 1) {
        if (threadIdx.x < s) red[threadIdx.x] += red[threadIdx.x + s];
        __syncthreads();
    }
    if (threadIdx.x == 0) atomicAdd(sse, (double)red[0]);
}

__global__ __launch_bounds__(1024) void finalize_kernel(const unsigned int* __restrict__ counts,
                                                        const double* __restrict__ sse,
                                                        float* __restrict__ out) {
    __shared__ double red[1024];
    const int t = threadIdx.x;
    double p = (double)counts[t] / (double)N_ROWS;
    red[t] = -p * log(p + 1e-10);
    __syncthreads();
#pragma unroll
    for (int s = 512; s > 0; s >>= 1) {
        if (t < s) red[t] += red[t + s];
        __syncthreads();
    }
    if (t == 0) {
        out[OUT_PERP] = (float)exp(red[0]);
        out[OUT_LOSS] = (float)(1.25 * (*sse) / (double)((size_t)N_ROWS * DIM));
    }
}

extern "C" void kernel_launch(void* const* d_in, const int* in_sizes, int n_in,
                              void* d_out, int out_size, void* d_ws, size_t ws_size,
                              hipStream_t stream) {
    const float* inp = (const float*)d_in[0];   // [32,64,64,64]
    const float* emb = (const float*)d_in[1];   // [1024,64]
    float* out = (float*)d_out;

    double*       sse    = (double*)d_ws;
    unsigned int* counts = (unsigned int*)((char*)d_ws + 16);
    float*        norms  = (float*)((char*)d_ws + 4112);

    hipMemsetAsync(d_ws, 0, 4112, stream);   // sse + counts
    embnorm_kernel<<<4, 256, 0, stream>>>(emb, norms);
    vq_kernel<<<512, 256, 0, stream>>>(inp, emb, norms, out, counts, sse);
    finalize_kernel<<<1, 1024, 0, stream>>>(counts, sse, out);
}

// Round 6
// 382.964 us; speedup vs baseline: 1.9934x; 1.9934x over previous
//
#include <hip/hip_runtime.h>

// Vector Quantizer (VQ-VAE) forward on MI355X.
// N=131072 rows, D=64, K=1024 codes, all fp32.
// Output (flat fp32): quantized[8388608] | loss[1] | perplexity[1] | indices[131072]
//
// Numerics (PROVEN round 3 — do not change): replicate np's fp32 distances
//   d_k = fp32( fp32(||x||^2 + ||e_k||^2) - fp32(2 * (x . e_k)) ), first-min argmin,
// dot = single sequential fmaf chain over d=0..63, decisive ops via __f*_rn.
//
// R6: rounds 3/5 proved xv[64] lives in SCRATCH (SROA runs before unrolling;
// runtime-indexed alloca -> private memory; VGPR_Count 64/52 with 55-67MB of
// spill writes, VALUBusy 35-55%). Fix: (1) x row in 16 NAMED float4 registers
// (no alloca at all); (2) two waves per row (k-halves, merged via LDS with
// strict-< so first-min semantics hold exactly) -> 1024 blocks = 4 waves/SIMD
// for FMA-latency coverage. Floor: 512*64 FMA * 2cy * 4 waves = 109us.

#define N_ROWS   131072
#define K_CODES  1024
#define DIM      64
#define OUT_LOSS 8388608
#define OUT_PERP 8388609
#define OUT_IDX  8388610

// ---------------- ws layout ----------------
// [0,8)        double sse
// [8,16)       pad
// [16,4112)    uint counts[1024]
// [4112,8208)  float embnorm[1024]

__global__ __launch_bounds__(256) void embnorm_kernel(const float* __restrict__ emb,
                                                      float* __restrict__ norms) {
    int k = blockIdx.x * blockDim.x + threadIdx.x;
    if (k < K_CODES) {
        const float* e = emb + (size_t)k * DIM;
        float r[8];
#pragma unroll
        for (int j = 0; j < 8; ++j) r[j] = __fmul_rn(e[j], e[j]);
#pragma unroll
        for (int i = 8; i < DIM; i += 8)
#pragma unroll
            for (int j = 0; j < 8; ++j) r[j] = __fadd_rn(r[j], __fmul_rn(e[i + j], e[i + j]));
        norms[k] = __fadd_rn(__fadd_rn(__fadd_rn(r[0], r[1]), __fadd_rn(r[2], r[3])),
                             __fadd_rn(__fadd_rn(r[4], r[5]), __fadd_rn(r[6], r[7])));
    }
}

__global__ __launch_bounds__(256) void vq_kernel(const float* __restrict__ inp,
                                                 const float* __restrict__ emb,
                                                 const float* __restrict__ norms,
                                                 float* __restrict__ out,
                                                 unsigned int* __restrict__ counts,
                                                 double* __restrict__ sse) {
    const int tid  = threadIdx.x;
    const int rloc = tid & 127;
    // wave-uniform half index (waves 0,1 -> half 0; waves 2,3 -> half 1);
    // readfirstlane makes uniformity provable -> e-addresses scalarizable.
    const int half = __builtin_amdgcn_readfirstlane(tid >> 7);
    const int row  = blockIdx.x * 128 + rloc;

    // ---- x row in 16 NAMED float4 registers (no alloca -> no scratch) ----
    const float4* xp = reinterpret_cast<const float4*>(inp + (size_t)row * DIM);
#define DECLX(i) float4 x##i = xp[i];
    DECLX(0)  DECLX(1)  DECLX(2)  DECLX(3)
    DECLX(4)  DECLX(5)  DECLX(6)  DECLX(7)
    DECLX(8)  DECLX(9)  DECLX(10) DECLX(11)
    DECLX(12) DECLX(13) DECLX(14) DECLX(15)

    // ---- s1 = ||x||^2, numpy 8-accumulator pairwise pattern (stride-8) ----
    float r0 = __fmul_rn(x0.x, x0.x), r1 = __fmul_rn(x0.y, x0.y);
    float r2 = __fmul_rn(x0.z, x0.z), r3 = __fmul_rn(x0.w, x0.w);
    float r4 = __fmul_rn(x1.x, x1.x), r5 = __fmul_rn(x1.y, x1.y);
    float r6 = __fmul_rn(x1.z, x1.z), r7 = __fmul_rn(x1.w, x1.w);
#define S1ACC(e, o) \
    r0 = __fadd_rn(r0, __fmul_rn(x##e.x, x##e.x)); \
    r1 = __fadd_rn(r1, __fmul_rn(x##e.y, x##e.y)); \
    r2 = __fadd_rn(r2, __fmul_rn(x##e.z, x##e.z)); \
    r3 = __fadd_rn(r3, __fmul_rn(x##e.w, x##e.w)); \
    r4 = __fadd_rn(r4, __fmul_rn(x##o.x, x##o.x)); \
    r5 = __fadd_rn(r5, __fmul_rn(x##o.y, x##o.y)); \
    r6 = __fadd_rn(r6, __fmul_rn(x##o.z, x##o.z)); \
    r7 = __fadd_rn(r7, __fmul_rn(x##o.w, x##o.w));
    S1ACC(2, 3) S1ACC(4, 5) S1ACC(6, 7) S1ACC(8, 9)
    S1ACC(10, 11) S1ACC(12, 13) S1ACC(14, 15)
    const float s1 = __fadd_rn(__fadd_rn(__fadd_rn(r0, r1), __fadd_rn(r2, r3)),
                               __fadd_rn(__fadd_rn(r4, r5), __fadd_rn(r6, r7)));

    // ---- argmin over this wave's 512-code half; np fp32 rounding exact ----
    const float4* ebase = reinterpret_cast<const float4*>(emb);
    const int kbeg = half << 9;
    float best = 3.402823466e38f;
    int   bidx = 0;
#define DOT4(i) { float4 ev = ep[i]; \
    acc = __builtin_fmaf(x##i.x, ev.x, acc); \
    acc = __builtin_fmaf(x##i.y, ev.y, acc); \
    acc = __builtin_fmaf(x##i.z, ev.z, acc); \
    acc = __builtin_fmaf(x##i.w, ev.w, acc); }
    for (int k = kbeg; k < kbeg + 512; ++k) {
        const float4* ep = ebase + ((size_t)k << 4);
        float acc = 0.f;                 // sgemm: single sequential fma chain
        DOT4(0)  DOT4(1)  DOT4(2)  DOT4(3)
        DOT4(4)  DOT4(5)  DOT4(6)  DOT4(7)
        DOT4(8)  DOT4(9)  DOT4(10) DOT4(11)
        DOT4(12) DOT4(13) DOT4(14) DOT4(15)
        float Dk = __fsub_rn(__fadd_rn(s1, norms[k]), __fmul_rn(2.0f, acc));
        if (Dk < best) { best = Dk; bidx = k; }   // strict <: first index wins
    }

    // ---- merge halves (strict <: lower-k half wins ties == np first-min) ----
    __shared__ float sbest[256];
    __shared__ int   sidx[256];
    __shared__ float red[256];
    sbest[tid] = best;
    sidx[tid]  = bidx;
    __syncthreads();

    float err = 0.f;
    if (tid < 128) {
        float ob = sbest[tid + 128];
        int   oi = sidx[tid + 128];
        if (ob < best) { best = ob; bidx = oi; }

        const float4* eb = ebase + ((size_t)bidx << 4);
        float4* qo = reinterpret_cast<float4*>(out + (size_t)row * DIM);
#define EPI(i) { float4 ev = eb[i]; qo[i] = ev; \
    float dx = ev.x - x##i.x, dy = ev.y - x##i.y; \
    float dz = ev.z - x##i.z, dw = ev.w - x##i.w; \
    err += dx * dx + dy * dy + dz * dz + dw * dw; }
        EPI(0)  EPI(1)  EPI(2)  EPI(3)
        EPI(4)  EPI(5)  EPI(6)  EPI(7)
        EPI(8)  EPI(9)  EPI(10) EPI(11)
        EPI(12) EPI(13) EPI(14) EPI(15)

        out[OUT_IDX + row] = (float)bidx;
        atomicAdd(&counts[bidx], 1u);
    }

    red[tid] = err;
    __syncthreads();
#pragma unroll
    for (int s = 128; s > 0; s >>= 1) {
        if (tid < s) red[tid] += red[tid + s];
        __syncthreads();
    }
    if (tid == 0) atomicAdd(sse, (double)red[0]);
}

__global__ __launch_bounds__(1024) void finalize_kernel(const unsigned int* __restrict__ counts,
                                                        const double* __restrict__ sse,
                                                        float* __restrict__ out) {
    __shared__ double red[1024];
    const int t = threadIdx.x;
    double p = (double)counts[t] / (double)N_ROWS;
    red[t] = -p * log(p + 1e-10);
    __syncthreads();
#pragma unroll
    for (int s = 512; s > 0; s >>= 1) {
        if (t < s) red[t] += red[t + s];
        __syncthreads();
    }
    if (t == 0) {
        out[OUT_PERP] = (float)exp(red[0]);
        out[OUT_LOSS] = (float)(1.25 * (*sse) / (double)((size_t)N_ROWS * DIM));
    }
}

extern "C" void kernel_launch(void* const* d_in, const int* in_sizes, int n_in,
                              void* d_out, int out_size, void* d_ws, size_t ws_size,
                              hipStream_t stream) {
    const float* inp = (const float*)d_in[0];   // [32,64,64,64]
    const float* emb = (const float*)d_in[1];   // [1024,64]
    float* out = (float*)d_out;

    double*       sse    = (double*)d_ws;
    unsigned int* counts = (unsigned int*)((char*)d_ws + 16);
    float*        norms  = (float*)((char*)d_ws + 4112);

    hipMemsetAsync(d_ws, 0, 4112, stream);   // sse + counts
    embnorm_kernel<<<4, 256, 0, stream>>>(emb, norms);
    vq_kernel<<<1024, 256, 0, stream>>>(inp, emb, norms, out, counts, sse);
    finalize_kernel<<<1, 1024, 0, stream>>>(counts, sse, out);
}